// Round 1
// baseline (237.603 us; speedup 1.0000x reference)
//
#include <hip/hip_runtime.h>
#include <hip/hip_fp16.h>

typedef _Float16 half8 __attribute__((ext_vector_type(8)));
typedef float floatx4 __attribute__((ext_vector_type(4)));

#define T_SEQ 2048
#define NB    8
#define HD    64

// ---------------------------------------------------------------------------
// Kernel 1: q = x @ Wq  (fp32 in, f16 out, row-major + transposed copies)
// 256 blocks x 512 threads; each wave computes 8 rows, lane = h.
// ---------------------------------------------------------------------------
__global__ __launch_bounds__(512) void qproj_kernel(
    const float* __restrict__ x, const float* __restrict__ Wq,
    _Float16* __restrict__ q16, _Float16* __restrict__ q16T)
{
  const int lane = threadIdx.x & 63;
  const int w    = threadIdx.x >> 6;
  const int rowbase = __builtin_amdgcn_readfirstlane((int)blockIdx.x * 64 + w * 8);
  const float* xr = x + (size_t)rowbase * 768;

  float acc[8];
  #pragma unroll
  for (int r = 0; r < 8; ++r) acc[r] = 0.f;

  for (int c = 0; c < 768; c += 4) {
    float w0 = Wq[(c + 0) * 64 + lane];
    float w1 = Wq[(c + 1) * 64 + lane];
    float w2 = Wq[(c + 2) * 64 + lane];
    float w3 = Wq[(c + 3) * 64 + lane];
    #pragma unroll
    for (int r = 0; r < 8; ++r) {
      float4 xv = *(const float4*)(xr + r * 768 + c);
      acc[r] = fmaf(xv.x, w0, acc[r]);
      acc[r] = fmaf(xv.y, w1, acc[r]);
      acc[r] = fmaf(xv.z, w2, acc[r]);
      acc[r] = fmaf(xv.w, w3, acc[r]);
    }
  }

  // row-major q16[row][h]
  #pragma unroll
  for (int r = 0; r < 8; ++r)
    q16[((size_t)(rowbase + r)) * 64 + lane] = (_Float16)acc[r];

  // transposed q16T[b][h][t] (lane h holds 8 consecutive t values -> 16B store)
  const int bb = rowbase >> 11;       // / 2048
  const int tt = rowbase & 2047;
  half8 hv;
  #pragma unroll
  for (int r = 0; r < 8; ++r) hv[r] = (_Float16)acc[r];
  *(float4*)(q16T + ((size_t)(bb * 64 + lane)) * T_SEQ + tt) =
      __builtin_bit_cast(float4, hv);
}

// ---------------------------------------------------------------------------
// Kernel 2: flash attention with causal mask + relative bias.
// 512 blocks x 128 threads (2 waves). Q-tile = 32 rows (16/wave), K-tile = 64.
// LDS rows padded to 72 f16 (2-way bank aliasing, free).
// ---------------------------------------------------------------------------
__global__ __launch_bounds__(128) void attn_kernel(
    const _Float16* __restrict__ q16, const _Float16* __restrict__ q16T,
    const float* __restrict__ rel_table, float* __restrict__ out)
{
  __shared__ __align__(16) _Float16 Krow[64 * 72];   // K rows   [s][h]
  __shared__ __align__(16) _Float16 Vt  [64 * 72];   // V^T      [h][s]
  __shared__ __align__(16) _Float16 Pbuf[2 * 16 * 72]; // per-wave P [t][s]
  __shared__ float biasLds[2176];                    // bias slice * log2e

  // balanced remap: first 256 blocks take even q-tiles ascending,
  // next 256 take odd q-tiles descending -> complementary causal work pairs.
  int b, qt;
  {
    int i = blockIdx.x;
    if (i < 256) { qt = 2 * (i & 31);      b = i >> 5; }
    else         { int j = i - 256; qt = 63 - 2 * (j & 31); b = j >> 5; }
  }
  const int t0  = qt * 32;
  const int nkt = (qt >> 1) + 1;          // K-tiles needed to cover diagonal

  const int tid  = threadIdx.x;
  const int w    = tid >> 6;
  const int lane = tid & 63;
  const int quad = lane >> 4;
  const int n    = lane & 15;
  const int tmin = t0 + 16 * w;

  // stage bias slice once (pre-scaled by log2e): idx_local = s - t + t0 + 31
  const int lo  = 2016 - t0;              // 2047 - (t0 + 31)
  const int cnt = t0 + 95;
  for (int k = tid; k < cnt; k += 128)
    biasLds[k] = rel_table[lo + k] * 1.44269504f;

  // Q fragments (A-operand): A[m=lane&15][k=quad*8+j], two 32-wide h chunks
  half8 aq[2];
  #pragma unroll
  for (int ch = 0; ch < 2; ++ch) {
    float4 t = *(const float4*)(q16 +
        ((size_t)(b * T_SEQ + t0 + 16 * w + n)) * 64 + ch * 32 + quad * 8);
    aq[ch] = __builtin_bit_cast(half8, t);
  }

  floatx4 O[4];
  #pragma unroll
  for (int s = 0; s < 4; ++s) O[s] = (floatx4){0.f, 0.f, 0.f, 0.f};
  float m_i[4], l_i[4];
  #pragma unroll
  for (int r = 0; r < 4; ++r) { m_i[r] = -1e30f; l_i[r] = 0.f; }

  _Float16* Pw = Pbuf + w * 16 * 72;
  const float kscale = 0.125f * 1.44269504f;  // (1/sqrt(64)) * log2e

  __syncthreads();

  for (int kt = 0; kt < nkt; ++kt) {
    const int s0 = kt * 64;

    // --- stage K rows + V^T (8 KB each, coalesced 16B loads) ---
    {
      int r = tid >> 1, hs = tid & 1;
      const float4* s1 = (const float4*)(q16 +
          ((size_t)(b * T_SEQ + s0 + r)) * 64 + hs * 32);
      float4* d1 = (float4*)(Krow + r * 72 + hs * 32);
      d1[0] = s1[0]; d1[1] = s1[1]; d1[2] = s1[2]; d1[3] = s1[3];
      const float4* s2 = (const float4*)(q16T +
          ((size_t)(b * 64 + r)) * T_SEQ + s0 + hs * 32);
      float4* d2 = (float4*)(Vt + r * 72 + hs * 32);
      d2[0] = s2[0]; d2[1] = s2[1]; d2[2] = s2[2]; d2[3] = s2[3];
    }
    __syncthreads();

    // --- S = Q K^T * scale + bias (log2 domain), with causal mask ---
    float xv[4][4];
    float xm[4] = {-1e30f, -1e30f, -1e30f, -1e30f};
    #pragma unroll
    for (int sub = 0; sub < 4; ++sub) {
      const int smin = s0 + 16 * sub;
      if (smin > tmin + 15) {             // fully masked sub-tile (uniform)
        #pragma unroll
        for (int r = 0; r < 4; ++r) xv[sub][r] = -1e30f;
        continue;
      }
      floatx4 sacc = (floatx4){0.f, 0.f, 0.f, 0.f};
      #pragma unroll
      for (int ch = 0; ch < 2; ++ch) {
        half8 bk = *(const half8*)(Krow + (sub * 16 + n) * 72 + ch * 32 + quad * 8);
        sacc = __builtin_amdgcn_mfma_f32_16x16x32_f16(aq[ch], bk, sacc, 0, 0, 0);
      }
      const int baseidx = smin + n - 16 * w + 31;   // minus (4*quad + r) below
      const bool part = (smin + 15 > tmin);         // straddles diagonal
      #pragma unroll
      for (int r = 0; r < 4; ++r) {
        float bv  = biasLds[baseidx - 4 * quad - r];
        float val = fmaf(sacc[r], kscale, bv);
        if (part) {
          int s = smin + n, t = tmin + 4 * quad + r;
          val = (s <= t) ? val : -1e30f;
        }
        xv[sub][r] = val;
        xm[r] = fmaxf(xm[r], val);
      }
    }

    // --- online softmax: row max over the 16 lanes of each quad ---
    #pragma unroll
    for (int off = 1; off < 16; off <<= 1) {
      #pragma unroll
      for (int r = 0; r < 4; ++r)
        xm[r] = fmaxf(xm[r], __shfl_xor(xm[r], off));
    }
    float al[4], ps[4];
    #pragma unroll
    for (int r = 0; r < 4; ++r) {
      float mn = fmaxf(m_i[r], xm[r]);
      al[r] = exp2f(m_i[r] - mn);
      m_i[r] = mn;
      ps[r] = 0.f;
    }
    #pragma unroll
    for (int sub = 0; sub < 4; ++sub) {
      #pragma unroll
      for (int r = 0; r < 4; ++r) {
        float p = exp2f(xv[sub][r] - m_i[r]);
        ps[r] += p;
        Pw[(4 * quad + r) * 72 + sub * 16 + n] = (_Float16)p;
      }
    }
    #pragma unroll
    for (int off = 1; off < 16; off <<= 1) {
      #pragma unroll
      for (int r = 0; r < 4; ++r)
        ps[r] += __shfl_xor(ps[r], off);
    }
    #pragma unroll
    for (int r = 0; r < 4; ++r) l_i[r] = l_i[r] * al[r] + ps[r];
    #pragma unroll
    for (int s = 0; s < 4; ++s) {
      #pragma unroll
      for (int r = 0; r < 4; ++r) O[s][r] *= al[r];
    }

    // --- O += P V  (A = P from LDS, B = V^T columns, contiguous b128) ---
    #pragma unroll
    for (int ch = 0; ch < 2; ++ch) {
      half8 pf = *(const half8*)(Pw + n * 72 + ch * 32 + quad * 8);
      #pragma unroll
      for (int sh = 0; sh < 4; ++sh) {
        half8 vf = *(const half8*)(Vt + (sh * 16 + n) * 72 + ch * 32 + quad * 8);
        O[sh] = __builtin_amdgcn_mfma_f32_16x16x32_f16(pf, vf, O[sh], 0, 0, 0);
      }
    }
    __syncthreads();
  }

  // --- epilogue: out = O / l ---
  #pragma unroll
  for (int r = 0; r < 4; ++r) l_i[r] = 1.0f / l_i[r];
  #pragma unroll
  for (int sh = 0; sh < 4; ++sh) {
    #pragma unroll
    for (int r = 0; r < 4; ++r)
      out[((size_t)(b * T_SEQ + tmin + 4 * quad + r)) * 64 + sh * 16 + n] =
          O[sh][r] * l_i[r];
  }
}

// ---------------------------------------------------------------------------
extern "C" void kernel_launch(void* const* d_in, const int* in_sizes, int n_in,
                              void* d_out, int out_size, void* d_ws, size_t ws_size,
                              hipStream_t stream) {
  const float* x   = (const float*)d_in[0];
  const float* Wq  = (const float*)d_in[1];
  const float* rel = (const float*)d_in[2];
  float* out = (float*)d_out;

  _Float16* q16  = (_Float16*)d_ws;                       // [8][2048][64] f16
  _Float16* q16T = q16 + (size_t)NB * T_SEQ * HD;         // [8][64][2048] f16

  qproj_kernel<<<256, 512, 0, stream>>>(x, Wq, q16, q16T);
  attn_kernel<<<512, 128, 0, stream>>>(q16, q16T, rel, out);
}

// Round 2
// 142.439 us; speedup vs baseline: 1.6681x; 1.6681x over previous
//
#include <hip/hip_runtime.h>
#include <hip/hip_fp16.h>

typedef _Float16 half8 __attribute__((ext_vector_type(8)));
typedef _Float16 half4 __attribute__((ext_vector_type(4)));
typedef float floatx4 __attribute__((ext_vector_type(4)));

#define T_SEQ 2048
#define NB    8

// ---------------------------------------------------------------------------
// Kernel 0: prep — WqT f16 [64][768] and bias*log2e table [4095]
// ---------------------------------------------------------------------------
__global__ __launch_bounds__(256) void prep_kernel(
    const float* __restrict__ Wq, const float* __restrict__ rel,
    _Float16* __restrict__ WqT, float* __restrict__ biasS)
{
  const int bid = blockIdx.x, tid = threadIdx.x;
  if (bid < 64) {
    for (int k = tid; k < 768; k += 256)
      WqT[bid * 768 + k] = (_Float16)Wq[k * 64 + bid];
  } else {
    for (int idx = tid; idx < 4095; idx += 256)
      biasS[idx] = rel[idx] * 1.44269504f;
  }
}

// ---------------------------------------------------------------------------
// Kernel 1: q = x @ Wq via f16 MFMA. No LDS, no barriers.
// 512 blocks x 128 threads (2 waves); wave computes 16 rows x 64 cols.
// A-frags straight from global x (coalesced 128B/row), B-frags from WqT (L2).
// ---------------------------------------------------------------------------
__global__ __launch_bounds__(128) void qproj_kernel(
    const float* __restrict__ x, const _Float16* __restrict__ WqT,
    _Float16* __restrict__ q16, _Float16* __restrict__ q16T)
{
  const int lane = threadIdx.x & 63;
  const int w    = threadIdx.x >> 6;
  const int n    = lane & 15, quad = lane >> 4;
  const int r0   = (blockIdx.x * 2 + w) * 16;

  const float*    xp = x   + (size_t)(r0 + n) * 768 + quad * 8;
  const _Float16* wp = WqT + (size_t)n * 768 + quad * 8;

  floatx4 acc[4];
  #pragma unroll
  for (int s = 0; s < 4; ++s) acc[s] = (floatx4){0.f, 0.f, 0.f, 0.f};

  #pragma unroll 2
  for (int ks = 0; ks < 768; ks += 32) {
    float4 x0 = *(const float4*)(xp + ks);
    float4 x1 = *(const float4*)(xp + ks + 4);
    half8 b0 = *(const half8*)(wp + ks);
    half8 b1 = *(const half8*)(wp + 16 * 768 + ks);
    half8 b2 = *(const half8*)(wp + 32 * 768 + ks);
    half8 b3 = *(const half8*)(wp + 48 * 768 + ks);
    half8 a;
    a[0] = (_Float16)x0.x; a[1] = (_Float16)x0.y;
    a[2] = (_Float16)x0.z; a[3] = (_Float16)x0.w;
    a[4] = (_Float16)x1.x; a[5] = (_Float16)x1.y;
    a[6] = (_Float16)x1.z; a[7] = (_Float16)x1.w;
    acc[0] = __builtin_amdgcn_mfma_f32_16x16x32_f16(a, b0, acc[0], 0, 0, 0);
    acc[1] = __builtin_amdgcn_mfma_f32_16x16x32_f16(a, b1, acc[1], 0, 0, 0);
    acc[2] = __builtin_amdgcn_mfma_f32_16x16x32_f16(a, b2, acc[2], 0, 0, 0);
    acc[3] = __builtin_amdgcn_mfma_f32_16x16x32_f16(a, b3, acc[3], 0, 0, 0);
  }

  // C layout: col = lane&15 (h sub), row = quad*4 + r
  const int bb = r0 >> 11;
  const int tt = (r0 & 2047) + quad * 4;
  #pragma unroll
  for (int sub = 0; sub < 4; ++sub) {
    #pragma unroll
    for (int r = 0; r < 4; ++r)
      q16[(size_t)(r0 + quad * 4 + r) * 64 + sub * 16 + n] =
          (_Float16)acc[sub][r];
    half4 hv;
    hv[0] = (_Float16)acc[sub][0]; hv[1] = (_Float16)acc[sub][1];
    hv[2] = (_Float16)acc[sub][2]; hv[3] = (_Float16)acc[sub][3];
    *(half4*)(q16T + (size_t)(bb * 64 + sub * 16 + n) * T_SEQ + tt) = hv;
  }
}

// ---------------------------------------------------------------------------
// Kernel 2: flash attention, in-block K-split across 8 waves.
// 1024 blocks x 512 threads; block = (batch, 16-row Q-tile); wave w takes
// K-tiles w, w+8, ... with private online-softmax state; LDS combine at end.
// No barriers inside the K-loop; K/V frags direct from global (L2-resident).
// ---------------------------------------------------------------------------
__global__ __launch_bounds__(512, 4) void attn_kernel(
    const _Float16* __restrict__ q16, const _Float16* __restrict__ q16T,
    const float* __restrict__ biasS, float* __restrict__ out)
{
  __shared__ float Obuf[8 * 16 * 65];               // 33280 B
  __shared__ float Mbuf[8 * 16], Lbuf[8 * 16];      // 1024 B
  __shared__ __align__(16) _Float16 Pbuf[8 * 16 * 72];  // 18432 B

  const int bi  = blockIdx.x;
  const int qi  = 127 - (bi >> 3);                  // heavy tiles first
  const int b   = bi & 7;
  const int t0  = qi * 16;
  const int nkt = (t0 >> 6) + 1;

  const int tid = threadIdx.x;
  const int w   = tid >> 6;
  const int lane = tid & 63;
  const int n = lane & 15, quad = lane >> 4;

  half8 aq0, aq1;
  {
    const _Float16* qrow = q16 + (size_t)(b * T_SEQ + t0 + n) * 64 + quad * 8;
    aq0 = *(const half8*)qrow;
    aq1 = *(const half8*)(qrow + 32);
  }

  floatx4 O[4];
  #pragma unroll
  for (int s = 0; s < 4; ++s) O[s] = (floatx4){0.f, 0.f, 0.f, 0.f};
  float m_i[4], l_i[4];
  #pragma unroll
  for (int r = 0; r < 4; ++r) { m_i[r] = -1e30f; l_i[r] = 0.f; }

  _Float16* Pw = Pbuf + w * (16 * 72);
  const float ksc  = 0.125f * 1.44269504f;
  const float* bptr = biasS + (2047 - t0 - 4 * quad);

  for (int kt = w; kt < nkt; kt += 8) {
    const int s0 = kt * 64;
    float xv[4][4];
    float xm[4] = {-1e30f, -1e30f, -1e30f, -1e30f};

    #pragma unroll
    for (int sub = 0; sub < 4; ++sub) {
      const int smin = s0 + sub * 16;
      if (smin > t0 + 15) {                 // fully masked (wave-uniform)
        #pragma unroll
        for (int r = 0; r < 4; ++r) xv[sub][r] = -1e30f;
        continue;
      }
      const _Float16* kp = q16 + (size_t)(b * T_SEQ + smin + n) * 64 + quad * 8;
      half8 bk0 = *(const half8*)kp;
      half8 bk1 = *(const half8*)(kp + 32);
      floatx4 sc = (floatx4){0.f, 0.f, 0.f, 0.f};
      sc = __builtin_amdgcn_mfma_f32_16x16x32_f16(aq0, bk0, sc, 0, 0, 0);
      sc = __builtin_amdgcn_mfma_f32_16x16x32_f16(aq1, bk1, sc, 0, 0, 0);
      const int  sIdx = smin + n;
      const bool part = (smin + 15 > t0);   // straddles diagonal
      #pragma unroll
      for (int r = 0; r < 4; ++r) {
        float val = fmaf(sc[r], ksc, bptr[sIdx - r]);
        if (part && sIdx > t0 + 4 * quad + r) val = -1e30f;
        xv[sub][r] = val;
        xm[r] = fmaxf(xm[r], val);
      }
    }

    // row-max over the 16 n-lanes (stays within quad)
    #pragma unroll
    for (int off = 1; off < 16; off <<= 1) {
      #pragma unroll
      for (int r = 0; r < 4; ++r)
        xm[r] = fmaxf(xm[r], __shfl_xor(xm[r], off));
    }
    float al[4], ps[4];
    #pragma unroll
    for (int r = 0; r < 4; ++r) {
      float mn = fmaxf(m_i[r], xm[r]);
      al[r] = exp2f(m_i[r] - mn);
      m_i[r] = mn;
      ps[r] = 0.f;
    }
    #pragma unroll
    for (int sub = 0; sub < 4; ++sub) {
      #pragma unroll
      for (int r = 0; r < 4; ++r) {
        float p = exp2f(xv[sub][r] - m_i[r]);
        ps[r] += p;
        Pw[(4 * quad + r) * 72 + sub * 16 + n] = (_Float16)p;
      }
    }
    #pragma unroll
    for (int off = 1; off < 16; off <<= 1) {
      #pragma unroll
      for (int r = 0; r < 4; ++r)
        ps[r] += __shfl_xor(ps[r], off);
    }
    #pragma unroll
    for (int r = 0; r < 4; ++r) l_i[r] = l_i[r] * al[r] + ps[r];
    #pragma unroll
    for (int s = 0; s < 4; ++s) {
      #pragma unroll
      for (int r = 0; r < 4; ++r) O[s][r] *= al[r];
    }

    // O += P V : A = P (per-wave LDS), B = V^T direct from global
    #pragma unroll
    for (int ch = 0; ch < 2; ++ch) {
      half8 pf = *(const half8*)(Pw + n * 72 + ch * 32 + quad * 8);
      #pragma unroll
      for (int sh = 0; sh < 4; ++sh) {
        half8 vf = *(const half8*)(q16T +
            (size_t)(b * 64 + sh * 16 + n) * T_SEQ + s0 + ch * 32 + quad * 8);
        O[sh] = __builtin_amdgcn_mfma_f32_16x16x32_f16(pf, vf, O[sh], 0, 0, 0);
      }
    }
  }

  // --- write per-wave partials ---
  #pragma unroll
  for (int sh = 0; sh < 4; ++sh)
    #pragma unroll
    for (int r = 0; r < 4; ++r)
      Obuf[(w * 16 + quad * 4 + r) * 65 + sh * 16 + n] = O[sh][r];
  if (n == 0) {
    #pragma unroll
    for (int r = 0; r < 4; ++r) {
      Mbuf[w * 16 + quad * 4 + r] = m_i[r];
      Lbuf[w * 16 + quad * 4 + r] = l_i[r];
    }
  }
  __syncthreads();

  // --- combine 8 wave-partials with rescaling ---
  for (int e = tid; e < 1024; e += 512) {
    const int row = e >> 6, h = e & 63;
    float M = -1e30f;
    #pragma unroll
    for (int w8 = 0; w8 < 8; ++w8) M = fmaxf(M, Mbuf[w8 * 16 + row]);
    float den = 0.f, num = 0.f;
    #pragma unroll
    for (int w8 = 0; w8 < 8; ++w8) {
      float a2 = exp2f(Mbuf[w8 * 16 + row] - M);
      den += a2 * Lbuf[w8 * 16 + row];
      num = fmaf(a2, Obuf[(w8 * 16 + row) * 65 + h], num);
    }
    out[(size_t)(b * T_SEQ + t0 + row) * 64 + h] = num / den;
  }
}

// ---------------------------------------------------------------------------
extern "C" void kernel_launch(void* const* d_in, const int* in_sizes, int n_in,
                              void* d_out, int out_size, void* d_ws, size_t ws_size,
                              hipStream_t stream) {
  const float* x   = (const float*)d_in[0];
  const float* Wq  = (const float*)d_in[1];
  const float* rel = (const float*)d_in[2];
  float* out = (float*)d_out;

  _Float16* q16   = (_Float16*)d_ws;                    // [8][2048][64]
  _Float16* q16T  = q16  + (size_t)NB * T_SEQ * 64;     // [8][64][2048]
  _Float16* WqT   = q16T + (size_t)NB * T_SEQ * 64;     // [64][768]
  float*    biasS = (float*)(WqT + 64 * 768);           // [4095]

  prep_kernel<<<65, 256, 0, stream>>>(Wq, rel, WqT, biasS);
  qproj_kernel<<<512, 128, 0, stream>>>(x, WqT, q16, q16T);
  attn_kernel<<<1024, 512, 0, stream>>>(q16, q16T, biasS, out);
}